// Round 13
// baseline (119.631 us; speedup 1.0000x reference)
//
#include <hip/hip_runtime.h>

constexpr int H = 4096;
constexpr int W = 4096;
constexpr int NPIX = H * W;           // 16,777,216
constexpr int W4   = W / 4;           // 1024 float4 per row
constexpr int NUNIT = 4 * H;          // 16384 quarter-row units
constexpr int K1_BLOCKS = 2048;
constexpr int K1_UNITS  = NUNIT / K1_BLOCKS;   // 8 units (2 rows) per block
constexpr int K2_BLOCKS = NUNIT / 2;  // 8192 blocks, 2 units (same row) each

typedef float f32x4 __attribute__((ext_vector_type(4)));

// XCD-aware bijective swizzle: give each of the 8 XCDs a contiguous block chunk
// so stencil-sharing neighbor rows (and the staged c) live in the same per-XCD L2.
__device__ __forceinline__ int xcd_swizzle(int b, int nper) {
    return (b & 7) * nper + (b >> 3);
}

// ---- wave64 reduce of 4 values ----
__device__ __forceinline__ void waveRed4(float& a, float& b, float& c, float& d) {
    #pragma unroll
    for (int o = 32; o > 0; o >>= 1) {
        a += __shfl_down(a, o, 64);
        b += __shfl_down(b, o, 64);
        c += __shfl_down(c, o, 64);
        d += __shfl_down(d, o, 64);
    }
}

// 3-tap horizontal conv for a float4 given left/right edge scalars
__device__ __forceinline__ float4 rowconv(float l, float4 c, float r, float f0, float f1, float f2) {
    float4 o;
    o.x = f0 * l   + f1 * c.x + f2 * c.y;
    o.y = f0 * c.x + f1 * c.y + f2 * c.z;
    o.z = f0 * c.y + f1 * c.z + f2 * c.w;
    o.w = f0 * c.z + f1 * c.w + f2 * r;
    return o;
}

// compute conv(p) float4 + center p float4 for unit u (quarter-row)
__device__ __forceinline__ void conv_unit(const float* __restrict__ p,
                                          const float f[9], int u,
                                          float4& cv_out, float4& pc_out) {
    const int h  = u >> 2;
    const int w4 = ((u & 3) << 8) + threadIdx.x;
    const int w0 = w4 << 2;

    const float* __restrict__ rowc = p + (size_t)h * W;
    const float* __restrict__ rowm = p + (size_t)(h > 0     ? h - 1 : 0    ) * W;
    const float* __restrict__ rowp = p + (size_t)(h < H - 1 ? h + 1 : H - 1) * W;
    const float mM = (h > 0)     ? 1.f : 0.f;
    const float pM = (h < H - 1) ? 1.f : 0.f;

    const float4 cm  = reinterpret_cast<const float4*>(rowm)[w4];
    const float4 cc4 = reinterpret_cast<const float4*>(rowc)[w4];
    const float4 cp  = reinterpret_cast<const float4*>(rowp)[w4];
    const int li = (w0 > 0) ? w0 - 1 : 0;
    const int ri = (w0 + 4 < W) ? w0 + 4 : W - 1;
    float lm = rowm[li], lc = rowc[li], lp = rowp[li];
    float rm = rowm[ri], rc = rowc[ri], rp = rowp[ri];

    const float lM = (w0 > 0) ? 1.f : 0.f;
    const float rM = (w0 + 4 < W) ? 1.f : 0.f;
    lm *= lM; lc *= lM; lp *= lM;
    rm *= rM; rc *= rM; rp *= rM;

    float4 cv = rowconv(lc, cc4, rc, f[3], f[4], f[5]);
    const float4 tm = rowconv(lm, cm, rm, f[0], f[1], f[2]);
    const float4 tp = rowconv(lp, cp, rp, f[6], f[7], f[8]);
    cv.x = fmaf(mM, tm.x, fmaf(pM, tp.x, cv.x));
    cv.y = fmaf(mM, tm.y, fmaf(pM, tp.y, cv.y));
    cv.z = fmaf(mM, tm.z, fmaf(pM, tp.z, cv.z));
    cv.w = fmaf(mM, tm.w, fmaf(pM, tp.w, cv.w));

    cv_out = cv;
    pc_out = cc4;
}

// ---- K1: partial sums over 8 units; stage conv(p) into out[p_new slot] ----
__global__ __launch_bounds__(256) void k1_sums(const float* __restrict__ r0,
                                               const float* __restrict__ p,
                                               const float* __restrict__ filt,
                                               float* __restrict__ out,
                                               float* __restrict__ partials) {
    __shared__ float sred[4][4];
    float f[9];
    #pragma unroll
    for (int i = 0; i < 9; ++i) f[i] = filt[i];

    const int lane = threadIdx.x & 63;
    const int wid  = threadIdx.x >> 6;
    const int sb   = xcd_swizzle(blockIdx.x, K1_BLOCKS / 8);

    f32x4* __restrict__ cstage = reinterpret_cast<f32x4*>(out + (size_t)NPIX);

    float s0 = 0.f, s1 = 0.f, s2 = 0.f, s3 = 0.f;
    const int u0 = sb * K1_UNITS;
    #pragma unroll 4
    for (int i = 0; i < K1_UNITS; ++i) {
        const int u = u0 + i;
        const int h  = u >> 2;
        const int w4 = ((u & 3) << 8) + threadIdx.x;
        const size_t vv = (size_t)h * W4 + w4;
        float4 cv, pc;
        conv_unit(p, f, u, cv, pc);
        const float4 rv = reinterpret_cast<const float4*>(r0 + (size_t)h * W)[w4];
        f32x4 cvv = { cv.x, cv.y, cv.z, cv.w };
        cstage[vv] = cvv;                       // plain store: keep in L2/L3 for k2
        s0 += rv.x*rv.x + rv.y*rv.y + rv.z*rv.z + rv.w*rv.w;
        s1 += pc.x*cv.x + pc.y*cv.y + pc.z*cv.z + pc.w*cv.w;
        s2 += rv.x*cv.x + rv.y*cv.y + rv.z*cv.z + rv.w*cv.w;
        s3 += cv.x*cv.x + cv.y*cv.y + cv.z*cv.z + cv.w*cv.w;
    }
    waveRed4(s0, s1, s2, s3);
    if (lane == 0) { sred[wid][0] = s0; sred[wid][1] = s1; sred[wid][2] = s2; sred[wid][3] = s3; }
    __syncthreads();
    if (threadIdx.x == 0) {
        f32x4 pv;
        pv.x = sred[0][0] + sred[1][0] + sred[2][0] + sred[3][0];
        pv.y = sred[0][1] + sred[1][1] + sred[2][1] + sred[3][1];
        pv.z = sred[0][2] + sred[1][2] + sred[2][2] + sred[3][2];
        pv.w = sred[0][3] + sred[1][3] + sred[2][3] + sred[3][3];
        reinterpret_cast<f32x4*>(partials)[blockIdx.x] = pv;
    }
}

// ---- K_reduce: fold 2048 partial-vectors, compute alpha, beta, r1_sum ----
__global__ __launch_bounds__(1024) void k_reduce(const float* __restrict__ partials,
                                                 float* __restrict__ scalars) {
    __shared__ float sred[16][4];
    const int lane = threadIdx.x & 63;
    const int wid  = threadIdx.x >> 6;

    f32x4 acc = reinterpret_cast<const f32x4*>(partials)[threadIdx.x]
              + reinterpret_cast<const f32x4*>(partials)[threadIdx.x + 1024];
    float s0 = acc.x, s1 = acc.y, s2 = acc.z, s3 = acc.w;
    waveRed4(s0, s1, s2, s3);
    if (lane == 0) { sred[wid][0] = s0; sred[wid][1] = s1; sred[wid][2] = s2; sred[wid][3] = s3; }
    __syncthreads();
    if (threadIdx.x == 0) {
        float rr0 = 0.f, pap = 0.f, r0c = 0.f, cc = 0.f;
        #pragma unroll
        for (int wv = 0; wv < 16; ++wv) {
            rr0 += sred[wv][0]; pap += sred[wv][1];
            r0c += sred[wv][2]; cc  += sred[wv][3];
        }
        const float alpha = rr0 / pap;
        const float r1s   = rr0 - 2.f * alpha * r0c + alpha * alpha * cc;
        scalars[0] = alpha;
        scalars[1] = r1s / rr0;   // beta
        scalars[2] = r1s;
    }
}

// ---- K2: pure stream update; c read from p_new slot then overwritten ----
// 2 quarter-row units per block (same row); XCD-swizzled to match k1's chunks
__global__ __launch_bounds__(256) void k2_update(const float* __restrict__ r0,
                                                 const float* __restrict__ p,
                                                 const float* __restrict__ phi,
                                                 const float* __restrict__ scalars,
                                                 float* __restrict__ out) {
    const float alpha = scalars[0];
    const float beta  = scalars[1];

    const int sb = xcd_swizzle(blockIdx.x, K2_BLOCKS / 8);

    f32x4* __restrict__ r1_out  = reinterpret_cast<f32x4*>(out);
    f32x4* __restrict__ pn_out  = reinterpret_cast<f32x4*>(out + (size_t)NPIX);
    f32x4* __restrict__ phi_out = reinterpret_cast<f32x4*>(out + 2 * (size_t)NPIX);

    #pragma unroll
    for (int k = 0; k < 2; ++k) {
        const int u = sb * 2 + k;
        const int h  = u >> 2;
        const int w4 = ((u & 3) << 8) + threadIdx.x;
        const size_t vv = (size_t)h * W4 + w4;

        const f32x4 cv = pn_out[vv];                                // staged conv(p), L2/L3 hit
        const f32x4 rv = reinterpret_cast<const f32x4*>(r0)[vv];
        const f32x4 pv = reinterpret_cast<const f32x4*>(p)[vv];
        const f32x4 ph = reinterpret_cast<const f32x4*>(phi)[vv];   // plain load: L3-retain phi

        f32x4 r1;
        r1.x = fmaf(-alpha, cv.x, rv.x);
        r1.y = fmaf(-alpha, cv.y, rv.y);
        r1.z = fmaf(-alpha, cv.z, rv.z);
        r1.w = fmaf(-alpha, cv.w, rv.w);
        f32x4 pn;
        pn.x = fmaf(beta, pv.x, r1.x);
        pn.y = fmaf(beta, pv.y, r1.y);
        pn.z = fmaf(beta, pv.z, r1.z);
        pn.w = fmaf(beta, pv.w, r1.w);
        f32x4 pho;
        pho.x = fmaf(alpha, pv.x, ph.x);
        pho.y = fmaf(alpha, pv.y, ph.y);
        pho.z = fmaf(alpha, pv.z, ph.z);
        pho.w = fmaf(alpha, pv.w, ph.w);

        __builtin_nontemporal_store(r1,  r1_out  + vv);
        pn_out[vv] = pn;                                            // overwrite staged c
        __builtin_nontemporal_store(pho, phi_out + vv);
    }
    if (blockIdx.x == 0 && threadIdx.x == 0) out[3 * (size_t)NPIX] = scalars[2];
}

extern "C" void kernel_launch(void* const* d_in, const int* in_sizes, int n_in,
                              void* d_out, int out_size, void* d_ws, size_t ws_size,
                              hipStream_t stream) {
    const float* r0   = (const float*)d_in[0];
    const float* p    = (const float*)d_in[1];
    const float* phi  = (const float*)d_in[2];
    const float* filt = (const float*)d_in[3];
    float* out      = (float*)d_out;
    float* partials = (float*)d_ws;                 // 4 * K1_BLOCKS floats
    float* scalars  = partials + 4 * K1_BLOCKS;     // alpha, beta, r1_sum

    hipLaunchKernelGGL(k1_sums,  dim3(K1_BLOCKS), dim3(256),  0, stream, r0, p, filt, out, partials);
    hipLaunchKernelGGL(k_reduce, dim3(1),         dim3(1024), 0, stream, partials, scalars);
    hipLaunchKernelGGL(k2_update,dim3(K2_BLOCKS), dim3(256),  0, stream, r0, p, phi, scalars, out);
}

// Round 14
// 104.626 us; speedup vs baseline: 1.1434x; 1.1434x over previous
//
#include <hip/hip_runtime.h>

constexpr int H = 4096;
constexpr int W = 4096;
constexpr int NPIX = H * W;           // 16,777,216
constexpr int W4   = W / 4;           // 1024 float4 per row
constexpr int NUNIT = 4 * H;          // 16384 quarter-row units
constexpr int K1_BLOCKS = 2048;
constexpr int K1_UNITS  = NUNIT / K1_BLOCKS;   // 8 units (2 rows) per block
constexpr int K2_BLOCKS = 8192;       // 4 qcols x 2048 row-pairs; 2 vertical units/block

typedef float f32x4 __attribute__((ext_vector_type(4)));

// XCD-aware bijective swizzle: give each of the 8 XCDs a contiguous block chunk
// so stencil-sharing neighbor rows live in the same per-XCD L2.
__device__ __forceinline__ int xcd_swizzle(int b, int nper) {
    return (b & 7) * nper + (b >> 3);
}

// ---- wave64 reduce of 4 values ----
__device__ __forceinline__ void waveRed4(float& a, float& b, float& c, float& d) {
    #pragma unroll
    for (int o = 32; o > 0; o >>= 1) {
        a += __shfl_down(a, o, 64);
        b += __shfl_down(b, o, 64);
        c += __shfl_down(c, o, 64);
        d += __shfl_down(d, o, 64);
    }
}

// 3-tap horizontal conv for a float4 given left/right edge scalars
__device__ __forceinline__ float4 rowconv(float l, float4 c, float r, float f0, float f1, float f2) {
    float4 o;
    o.x = f0 * l   + f1 * c.x + f2 * c.y;
    o.y = f0 * c.x + f1 * c.y + f2 * c.z;
    o.z = f0 * c.y + f1 * c.z + f2 * c.w;
    o.w = f0 * c.z + f1 * c.w + f2 * r;
    return o;
}

// compute conv(p) float4 + center p float4 for unit u (quarter-row)
__device__ __forceinline__ void conv_unit(const float* __restrict__ p,
                                          const float f[9], int u,
                                          float4& cv_out, float4& pc_out) {
    const int h  = u >> 2;
    const int w4 = ((u & 3) << 8) + threadIdx.x;
    const int w0 = w4 << 2;

    const float* __restrict__ rowc = p + (size_t)h * W;
    const float* __restrict__ rowm = p + (size_t)(h > 0     ? h - 1 : 0    ) * W;
    const float* __restrict__ rowp = p + (size_t)(h < H - 1 ? h + 1 : H - 1) * W;
    const float mM = (h > 0)     ? 1.f : 0.f;
    const float pM = (h < H - 1) ? 1.f : 0.f;

    const float4 cm  = reinterpret_cast<const float4*>(rowm)[w4];
    const float4 cc4 = reinterpret_cast<const float4*>(rowc)[w4];
    const float4 cp  = reinterpret_cast<const float4*>(rowp)[w4];
    const int li = (w0 > 0) ? w0 - 1 : 0;
    const int ri = (w0 + 4 < W) ? w0 + 4 : W - 1;
    float lm = rowm[li], lc = rowc[li], lp = rowp[li];
    float rm = rowm[ri], rc = rowc[ri], rp = rowp[ri];

    const float lM = (w0 > 0) ? 1.f : 0.f;
    const float rM = (w0 + 4 < W) ? 1.f : 0.f;
    lm *= lM; lc *= lM; lp *= lM;
    rm *= rM; rc *= rM; rp *= rM;

    float4 cv = rowconv(lc, cc4, rc, f[3], f[4], f[5]);
    const float4 tm = rowconv(lm, cm, rm, f[0], f[1], f[2]);
    const float4 tp = rowconv(lp, cp, rp, f[6], f[7], f[8]);
    cv.x = fmaf(mM, tm.x, fmaf(pM, tp.x, cv.x));
    cv.y = fmaf(mM, tm.y, fmaf(pM, tp.y, cv.y));
    cv.z = fmaf(mM, tm.z, fmaf(pM, tp.z, cv.z));
    cv.w = fmaf(mM, tm.w, fmaf(pM, tp.w, cv.w));

    cv_out = cv;
    pc_out = cc4;
}

// ---- K1: per-block partial sums over 8 units (2 adjacent rows) ----
__global__ __launch_bounds__(256) void k1_sums(const float* __restrict__ r0,
                                               const float* __restrict__ p,
                                               const float* __restrict__ filt,
                                               float* __restrict__ partials) {
    __shared__ float sred[4][4];
    float f[9];
    #pragma unroll
    for (int i = 0; i < 9; ++i) f[i] = filt[i];

    const int lane = threadIdx.x & 63;
    const int wid  = threadIdx.x >> 6;
    const int sb   = xcd_swizzle(blockIdx.x, K1_BLOCKS / 8);

    float s0 = 0.f, s1 = 0.f, s2 = 0.f, s3 = 0.f;
    const int u0 = sb * K1_UNITS;
    #pragma unroll 4
    for (int i = 0; i < K1_UNITS; ++i) {
        const int u = u0 + i;
        const int h  = u >> 2;
        const int w4 = ((u & 3) << 8) + threadIdx.x;
        float4 cv, pc;
        conv_unit(p, f, u, cv, pc);
        const float4 rv = reinterpret_cast<const float4*>(r0 + (size_t)h * W)[w4];
        s0 += rv.x*rv.x + rv.y*rv.y + rv.z*rv.z + rv.w*rv.w;
        s1 += pc.x*cv.x + pc.y*cv.y + pc.z*cv.z + pc.w*cv.w;
        s2 += rv.x*cv.x + rv.y*cv.y + rv.z*cv.z + rv.w*cv.w;
        s3 += cv.x*cv.x + cv.y*cv.y + cv.z*cv.z + cv.w*cv.w;
    }
    waveRed4(s0, s1, s2, s3);
    if (lane == 0) { sred[wid][0] = s0; sred[wid][1] = s1; sred[wid][2] = s2; sred[wid][3] = s3; }
    __syncthreads();
    if (threadIdx.x == 0) {
        f32x4 pv;
        pv.x = sred[0][0] + sred[1][0] + sred[2][0] + sred[3][0];
        pv.y = sred[0][1] + sred[1][1] + sred[2][1] + sred[3][1];
        pv.z = sred[0][2] + sred[1][2] + sred[2][2] + sred[3][2];
        pv.w = sred[0][3] + sred[1][3] + sred[2][3] + sred[3][3];
        reinterpret_cast<f32x4*>(partials)[blockIdx.x] = pv;
    }
}

// ---- K_reduce: fold 2048 partial-vectors, compute alpha, beta, r1_sum ----
__global__ __launch_bounds__(1024) void k_reduce(const float* __restrict__ partials,
                                                 float* __restrict__ scalars) {
    __shared__ float sred[16][4];
    const int lane = threadIdx.x & 63;
    const int wid  = threadIdx.x >> 6;

    f32x4 acc = reinterpret_cast<const f32x4*>(partials)[threadIdx.x]
              + reinterpret_cast<const f32x4*>(partials)[threadIdx.x + 1024];
    float s0 = acc.x, s1 = acc.y, s2 = acc.z, s3 = acc.w;
    waveRed4(s0, s1, s2, s3);
    if (lane == 0) { sred[wid][0] = s0; sred[wid][1] = s1; sred[wid][2] = s2; sred[wid][3] = s3; }
    __syncthreads();
    if (threadIdx.x == 0) {
        float rr0 = 0.f, pap = 0.f, r0c = 0.f, cc = 0.f;
        #pragma unroll
        for (int wv = 0; wv < 16; ++wv) {
            rr0 += sred[wv][0]; pap += sred[wv][1];
            r0c += sred[wv][2]; cc  += sred[wv][3];
        }
        const float alpha = rr0 / pap;
        const float r1s   = rr0 - 2.f * alpha * r0c + alpha * alpha * cc;
        scalars[0] = alpha;
        scalars[1] = r1s / rr0;   // beta
        scalars[2] = r1s;
    }
}

// ---- K2: r1 = r0 - alpha*c; p_new = r1 + beta*p; phi_new = phi + alpha*p ----
// 2 VERTICALLY adjacent quarter-row units per block (rows h,h+1, same columns):
// their stencil row-sets overlap in rows h,h+1 -> wide loads hit L1/L2.
__global__ __launch_bounds__(256) void k2_update(const float* __restrict__ r0,
                                                 const float* __restrict__ p,
                                                 const float* __restrict__ phi,
                                                 const float* __restrict__ filt,
                                                 const float* __restrict__ scalars,
                                                 float* __restrict__ out) {
    const float alpha = scalars[0];
    const float beta  = scalars[1];

    float f[9];
    #pragma unroll
    for (int i = 0; i < 9; ++i) f[i] = filt[i];

    const int sb = xcd_swizzle(blockIdx.x, K2_BLOCKS / 8);
    const int qc = sb & 3;            // quarter-column 0..3
    const int h0 = (sb >> 2) << 1;    // even row of the vertical pair

    f32x4* __restrict__ r1_out  = reinterpret_cast<f32x4*>(out);
    f32x4* __restrict__ pn_out  = reinterpret_cast<f32x4*>(out + (size_t)NPIX);
    f32x4* __restrict__ phi_out = reinterpret_cast<f32x4*>(out + 2 * (size_t)NPIX);

    #pragma unroll
    for (int k = 0; k < 2; ++k) {
        const int h = h0 + k;
        const int u = (h << 2) | qc;
        const int w4 = (qc << 8) + threadIdx.x;
        const size_t vv = (size_t)h * W4 + w4;

        float4 cv, pc;
        conv_unit(p, f, u, cv, pc);
        const float4 rv = reinterpret_cast<const float4*>(r0 + (size_t)h * W)[w4];
        const f32x4 ph = reinterpret_cast<const f32x4*>(phi)[vv];   // plain load: L3-retain phi

        f32x4 r1;
        r1.x = fmaf(-alpha, cv.x, rv.x);
        r1.y = fmaf(-alpha, cv.y, rv.y);
        r1.z = fmaf(-alpha, cv.z, rv.z);
        r1.w = fmaf(-alpha, cv.w, rv.w);
        f32x4 pn;
        pn.x = fmaf(beta, pc.x, r1.x);
        pn.y = fmaf(beta, pc.y, r1.y);
        pn.z = fmaf(beta, pc.z, r1.z);
        pn.w = fmaf(beta, pc.w, r1.w);
        f32x4 pho;
        pho.x = fmaf(alpha, pc.x, ph.x);
        pho.y = fmaf(alpha, pc.y, ph.y);
        pho.z = fmaf(alpha, pc.z, ph.z);
        pho.w = fmaf(alpha, pc.w, ph.w);

        __builtin_nontemporal_store(r1,  r1_out  + vv);
        __builtin_nontemporal_store(pn,  pn_out  + vv);
        __builtin_nontemporal_store(pho, phi_out + vv);
    }
    if (blockIdx.x == 0 && threadIdx.x == 0) out[3 * (size_t)NPIX] = scalars[2];
}

extern "C" void kernel_launch(void* const* d_in, const int* in_sizes, int n_in,
                              void* d_out, int out_size, void* d_ws, size_t ws_size,
                              hipStream_t stream) {
    const float* r0   = (const float*)d_in[0];
    const float* p    = (const float*)d_in[1];
    const float* phi  = (const float*)d_in[2];
    const float* filt = (const float*)d_in[3];
    float* out      = (float*)d_out;
    float* partials = (float*)d_ws;                 // 4 * K1_BLOCKS floats
    float* scalars  = partials + 4 * K1_BLOCKS;     // alpha, beta, r1_sum

    hipLaunchKernelGGL(k1_sums,  dim3(K1_BLOCKS), dim3(256),  0, stream, r0, p, filt, partials);
    hipLaunchKernelGGL(k_reduce, dim3(1),         dim3(1024), 0, stream, partials, scalars);
    hipLaunchKernelGGL(k2_update,dim3(K2_BLOCKS), dim3(256),  0, stream, r0, p, phi, filt, scalars, out);
}

// Round 16
// 103.803 us; speedup vs baseline: 1.1525x; 1.0079x over previous
//
#include <hip/hip_runtime.h>

constexpr int H = 4096;
constexpr int W = 4096;
constexpr int NPIX = H * W;           // 16,777,216
constexpr int W4   = W / 4;           // 1024 float4 per row
constexpr int K1_BLOCKS = 2048;       // 2 rows x 4 qcols (8 units) per block
constexpr int K2_BLOCKS = 8192;       // 2 vertical units per block

typedef float f32x4 __attribute__((ext_vector_type(4)));

// XCD-aware bijective swizzle: give each of the 8 XCDs a contiguous block chunk
// so stencil-sharing neighbor rows live in the same per-XCD L2.
__device__ __forceinline__ int xcd_swizzle(int b, int nper) {
    return (b & 7) * nper + (b >> 3);
}

// ---- wave64 reduce of 4 values ----
__device__ __forceinline__ void waveRed4(float& a, float& b, float& c, float& d) {
    #pragma unroll
    for (int o = 32; o > 0; o >>= 1) {
        a += __shfl_down(a, o, 64);
        b += __shfl_down(b, o, 64);
        c += __shfl_down(c, o, 64);
        d += __shfl_down(d, o, 64);
    }
}

// 3-tap horizontal conv for a float4 given left/right edge scalars
__device__ __forceinline__ float4 rowconv(float l, float4 c, float r, float f0, float f1, float f2) {
    float4 o;
    o.x = f0 * l   + f1 * c.x + f2 * c.y;
    o.y = f0 * c.x + f1 * c.y + f2 * c.z;
    o.z = f0 * c.y + f1 * c.z + f2 * c.w;
    o.w = f0 * c.z + f1 * c.w + f2 * r;
    return o;
}

// compute conv(p) float4 + center p float4 for unit u (quarter-row)
__device__ __forceinline__ void conv_unit(const float* __restrict__ p,
                                          const float f[9], int u,
                                          float4& cv_out, float4& pc_out) {
    const int h  = u >> 2;
    const int w4 = ((u & 3) << 8) + threadIdx.x;
    const int w0 = w4 << 2;

    const float* __restrict__ rowc = p + (size_t)h * W;
    const float* __restrict__ rowm = p + (size_t)(h > 0     ? h - 1 : 0    ) * W;
    const float* __restrict__ rowp = p + (size_t)(h < H - 1 ? h + 1 : H - 1) * W;
    const float mM = (h > 0)     ? 1.f : 0.f;
    const float pM = (h < H - 1) ? 1.f : 0.f;

    const float4 cm  = reinterpret_cast<const float4*>(rowm)[w4];
    const float4 cc4 = reinterpret_cast<const float4*>(rowc)[w4];
    const float4 cp  = reinterpret_cast<const float4*>(rowp)[w4];
    const int li = (w0 > 0) ? w0 - 1 : 0;
    const int ri = (w0 + 4 < W) ? w0 + 4 : W - 1;
    float lm = rowm[li], lc = rowc[li], lp = rowp[li];
    float rm = rowm[ri], rc = rowc[ri], rp = rowp[ri];

    const float lM = (w0 > 0) ? 1.f : 0.f;
    const float rM = (w0 + 4 < W) ? 1.f : 0.f;
    lm *= lM; lc *= lM; lp *= lM;
    rm *= rM; rc *= rM; rp *= rM;

    float4 cv = rowconv(lc, cc4, rc, f[3], f[4], f[5]);
    const float4 tm = rowconv(lm, cm, rm, f[0], f[1], f[2]);
    const float4 tp = rowconv(lp, cp, rp, f[6], f[7], f[8]);
    cv.x = fmaf(mM, tm.x, fmaf(pM, tp.x, cv.x));
    cv.y = fmaf(mM, tm.y, fmaf(pM, tp.y, cv.y));
    cv.z = fmaf(mM, tm.z, fmaf(pM, tp.z, cv.z));
    cv.w = fmaf(mM, tm.w, fmaf(pM, tp.w, cv.w));

    cv_out = cv;
    pc_out = cc4;
}

// ---- K1: per-block partial sums over 2 rows x 4 qcols, column-major order
//      (vertical pair back-to-back -> L1 reuse of shared stencil rows) ----
__global__ __launch_bounds__(256) void k1_sums(const float* __restrict__ r0,
                                               const float* __restrict__ p,
                                               const float* __restrict__ filt,
                                               float* __restrict__ partials) {
    __shared__ float sred[4][4];
    float f[9];
    #pragma unroll
    for (int i = 0; i < 9; ++i) f[i] = filt[i];

    const int lane = threadIdx.x & 63;
    const int wid  = threadIdx.x >> 6;
    const int sb   = xcd_swizzle(blockIdx.x, K1_BLOCKS / 8);
    const int h0   = sb * 2;

    float s0 = 0.f, s1 = 0.f, s2 = 0.f, s3 = 0.f;
    #pragma unroll 2
    for (int qc = 0; qc < 4; ++qc) {
        #pragma unroll
        for (int dh = 0; dh < 2; ++dh) {
            const int h = h0 + dh;
            const int u = (h << 2) | qc;
            const int w4 = (qc << 8) + threadIdx.x;
            float4 cv, pc;
            conv_unit(p, f, u, cv, pc);
            const float4 rv = reinterpret_cast<const float4*>(r0 + (size_t)h * W)[w4];
            s0 += rv.x*rv.x + rv.y*rv.y + rv.z*rv.z + rv.w*rv.w;
            s1 += pc.x*cv.x + pc.y*cv.y + pc.z*cv.z + pc.w*cv.w;
            s2 += rv.x*cv.x + rv.y*cv.y + rv.z*cv.z + rv.w*cv.w;
            s3 += cv.x*cv.x + cv.y*cv.y + cv.z*cv.z + cv.w*cv.w;
        }
    }
    waveRed4(s0, s1, s2, s3);
    if (lane == 0) { sred[wid][0] = s0; sred[wid][1] = s1; sred[wid][2] = s2; sred[wid][3] = s3; }
    __syncthreads();
    if (threadIdx.x == 0) {
        f32x4 pv;
        pv.x = sred[0][0] + sred[1][0] + sred[2][0] + sred[3][0];
        pv.y = sred[0][1] + sred[1][1] + sred[2][1] + sred[3][1];
        pv.z = sred[0][2] + sred[1][2] + sred[2][2] + sred[3][2];
        pv.w = sred[0][3] + sred[1][3] + sred[2][3] + sred[3][3];
        reinterpret_cast<f32x4*>(partials)[blockIdx.x] = pv;
    }
}

// ---- K_reduce: fold 2048 partial-vectors, compute alpha, beta, r1_sum ----
__global__ __launch_bounds__(1024) void k_reduce(const float* __restrict__ partials,
                                                 float* __restrict__ scalars) {
    __shared__ float sred[16][4];
    const int lane = threadIdx.x & 63;
    const int wid  = threadIdx.x >> 6;

    f32x4 acc = reinterpret_cast<const f32x4*>(partials)[threadIdx.x]
              + reinterpret_cast<const f32x4*>(partials)[threadIdx.x + 1024];
    float s0 = acc.x, s1 = acc.y, s2 = acc.z, s3 = acc.w;
    waveRed4(s0, s1, s2, s3);
    if (lane == 0) { sred[wid][0] = s0; sred[wid][1] = s1; sred[wid][2] = s2; sred[wid][3] = s3; }
    __syncthreads();
    if (threadIdx.x == 0) {
        float rr0 = 0.f, pap = 0.f, r0c = 0.f, cc = 0.f;
        #pragma unroll
        for (int wv = 0; wv < 16; ++wv) {
            rr0 += sred[wv][0]; pap += sred[wv][1];
            r0c += sred[wv][2]; cc  += sred[wv][3];
        }
        const float alpha = rr0 / pap;
        const float r1s   = rr0 - 2.f * alpha * r0c + alpha * alpha * cc;
        scalars[0] = alpha;
        scalars[1] = r1s / rr0;   // beta
        scalars[2] = r1s;
    }
}

// ---- K2: r1 = r0 - alpha*c; p_new = r1 + beta*p; phi_new = phi + alpha*p ----
// 2 VERTICALLY adjacent quarter-row units per block (rows h,h+1, same columns):
// their stencil row-sets overlap in rows h,h+1 -> wide loads hit L1/L2.
__global__ __launch_bounds__(256) void k2_update(const float* __restrict__ r0,
                                                 const float* __restrict__ p,
                                                 const float* __restrict__ phi,
                                                 const float* __restrict__ filt,
                                                 const float* __restrict__ scalars,
                                                 float* __restrict__ out) {
    const float alpha = scalars[0];
    const float beta  = scalars[1];

    float f[9];
    #pragma unroll
    for (int i = 0; i < 9; ++i) f[i] = filt[i];

    const int sb = xcd_swizzle(blockIdx.x, K2_BLOCKS / 8);
    const int qc = sb & 3;            // quarter-column 0..3
    const int h0 = (sb >> 2) << 1;    // even row of the vertical pair

    f32x4* __restrict__ r1_out  = reinterpret_cast<f32x4*>(out);
    f32x4* __restrict__ pn_out  = reinterpret_cast<f32x4*>(out + (size_t)NPIX);
    f32x4* __restrict__ phi_out = reinterpret_cast<f32x4*>(out + 2 * (size_t)NPIX);

    #pragma unroll
    for (int k = 0; k < 2; ++k) {
        const int h = h0 + k;
        const int u = (h << 2) | qc;
        const int w4 = (qc << 8) + threadIdx.x;
        const size_t vv = (size_t)h * W4 + w4;

        float4 cv, pc;
        conv_unit(p, f, u, cv, pc);
        const float4 rv = reinterpret_cast<const float4*>(r0 + (size_t)h * W)[w4];
        const f32x4 ph = reinterpret_cast<const f32x4*>(phi)[vv];   // plain load: L3-retain phi

        f32x4 r1;
        r1.x = fmaf(-alpha, cv.x, rv.x);
        r1.y = fmaf(-alpha, cv.y, rv.y);
        r1.z = fmaf(-alpha, cv.z, rv.z);
        r1.w = fmaf(-alpha, cv.w, rv.w);
        f32x4 pn;
        pn.x = fmaf(beta, pc.x, r1.x);
        pn.y = fmaf(beta, pc.y, r1.y);
        pn.z = fmaf(beta, pc.z, r1.z);
        pn.w = fmaf(beta, pc.w, r1.w);
        f32x4 pho;
        pho.x = fmaf(alpha, pc.x, ph.x);
        pho.y = fmaf(alpha, pc.y, ph.y);
        pho.z = fmaf(alpha, pc.z, ph.z);
        pho.w = fmaf(alpha, pc.w, ph.w);

        __builtin_nontemporal_store(r1,  r1_out  + vv);
        __builtin_nontemporal_store(pn,  pn_out  + vv);
        __builtin_nontemporal_store(pho, phi_out + vv);
    }
    if (blockIdx.x == 0 && threadIdx.x == 0) out[3 * (size_t)NPIX] = scalars[2];
}

extern "C" void kernel_launch(void* const* d_in, const int* in_sizes, int n_in,
                              void* d_out, int out_size, void* d_ws, size_t ws_size,
                              hipStream_t stream) {
    const float* r0   = (const float*)d_in[0];
    const float* p    = (const float*)d_in[1];
    const float* phi  = (const float*)d_in[2];
    const float* filt = (const float*)d_in[3];
    float* out      = (float*)d_out;
    float* partials = (float*)d_ws;                 // 4 * K1_BLOCKS floats
    float* scalars  = partials + 4 * K1_BLOCKS;     // alpha, beta, r1_sum

    hipLaunchKernelGGL(k1_sums,  dim3(K1_BLOCKS), dim3(256),  0, stream, r0, p, filt, partials);
    hipLaunchKernelGGL(k_reduce, dim3(1),         dim3(1024), 0, stream, partials, scalars);
    hipLaunchKernelGGL(k2_update,dim3(K2_BLOCKS), dim3(256),  0, stream, r0, p, phi, filt, scalars, out);
}